// Round 9
// baseline (1345.274 us; speedup 1.0000x reference)
//
#include <hip/hip_runtime.h>
#include <hip/hip_bf16.h>

using bf16x8 = __attribute__((ext_vector_type(8))) short;
using f32x4  = __attribute__((ext_vector_type(4))) float;
using u16x4  = __attribute__((ext_vector_type(4))) unsigned short;

#define DEVI static __device__ __forceinline__

DEVI unsigned short f2b(float f) {           // f32 -> bf16 RNE
  unsigned int u = __float_as_uint(f);
  u += 0x7FFFu + ((u >> 16) & 1u);
  return (unsigned short)(u >> 16);
}

DEVI void gload16(const unsigned short* g, unsigned short* l) {
  __builtin_amdgcn_global_load_lds(
      (const __attribute__((address_space(1))) unsigned int*)g,
      (__attribute__((address_space(3))) unsigned int*)l, 16, 0, 0);
}

DEVI float wred_max16(float v) {
#pragma unroll
  for (int m = 1; m < 16; m <<= 1) v = fmaxf(v, __shfl_xor(v, m, 64));
  return v;
}
DEVI float wred_sum16(float v) {
#pragma unroll
  for (int m = 1; m < 16; m <<= 1) v += __shfl_xor(v, m, 64);
  return v;
}

// ---------------- elementwise / pack kernels ----------------

__global__ void cvt_kernel(const float* __restrict__ in,
                           unsigned short* __restrict__ out, int n4) {
  int i = blockIdx.x * blockDim.x + threadIdx.x;
  const int stride = gridDim.x * blockDim.x;
  for (; i < n4; i += stride) {
    const float4 v = ((const float4*)in)[i];
    u16x4 o;
    o[0] = f2b(v.x); o[1] = f2b(v.y); o[2] = f2b(v.z); o[3] = f2b(v.w);
    ((u16x4*)out)[i] = o;
  }
}

// Pack rows of up to 3 source weight tensors ([L][2][1024][1024] f32, sub-slot
// `sub`) into a fused bf16 buffer dst[l][nm*1024][1024].
__global__ void pack_w(const float* __restrict__ s0,
                       const float* __restrict__ s1,
                       const float* __restrict__ s2,
                       int sub, unsigned short* __restrict__ dst, int nm) {
  const int r = blockIdx.x;      // row 0..1023
  const int m = blockIdx.y;      // matrix slot
  const int l = blockIdx.z;      // layer
  const float* src = (m == 0 ? s0 : m == 1 ? s1 : s2)
                   + (size_t)(l * 2 + sub) * 1048576 + (size_t)r * 1024;
  unsigned short* d = dst + ((size_t)(l * nm + m) * 1024 + r) * 1024;
  const int col = threadIdx.x * 4;
  const float4 v = *(const float4*)(src + col);
  u16x4 o;
  o[0] = f2b(v.x); o[1] = f2b(v.y); o[2] = f2b(v.z); o[3] = f2b(v.w);
  *(u16x4*)(d + col) = o;
}

__global__ void pack_bias(const float* __restrict__ s0,
                          const float* __restrict__ s1,
                          const float* __restrict__ s2,
                          int sub, float* __restrict__ dst, int nm) {
  const int m = blockIdx.x, l = blockIdx.y;
  const float* src = (m == 0 ? s0 : m == 1 ? s1 : s2) + (size_t)(l * 2 + sub) * 1024;
  float* d = dst + ((size_t)l * nm + m) * 1024;
  const int i = threadIdx.x * 4;
  *(float4*)(d + i) = *(const float4*)(src + i);
}

__global__ void embed_kernel(const int* __restrict__ ids,
                             const float* __restrict__ emb,
                             const float* __restrict__ pe,
                             float* __restrict__ x) {
  const int row = blockIdx.x;           // b*512 + t
  const int t = row & 511;
  const int col = threadIdx.x * 4;      // 256 threads
  const int id = ids[row];
  const float4 e = *(const float4*)(emb + (size_t)id * 1024 + col);
  const float4 p = *(const float4*)(pe + (size_t)t * 1024 + col);
  float4 o;
  o.x = e.x * 32.f + p.x; o.y = e.y * 32.f + p.y;
  o.z = e.z * 32.f + p.z; o.w = e.w * 32.f + p.w;
  *(float4*)(x + (size_t)row * 1024 + col) = o;
}

__global__ void ln_kernel(const float* __restrict__ x,
                          const float* __restrict__ g,
                          const float* __restrict__ b,
                          unsigned short* __restrict__ out) {
  const int row = blockIdx.x;
  const int l = threadIdx.x;            // 64 lanes, 16 elems each
  const float4* xr = (const float4*)(x + (size_t)row * 1024);
  float4 v[4];
  float s = 0.f;
#pragma unroll
  for (int i = 0; i < 4; ++i) {
    v[i] = xr[l * 4 + i];
    s += v[i].x + v[i].y + v[i].z + v[i].w;
  }
#pragma unroll
  for (int m = 1; m < 64; m <<= 1) s += __shfl_xor(s, m, 64);
  const float mean = s * (1.f / 1024.f);
  float vs = 0.f;
#pragma unroll
  for (int i = 0; i < 4; ++i) {
    float dx = v[i].x - mean, dy = v[i].y - mean, dz = v[i].z - mean, dw = v[i].w - mean;
    vs += dx * dx + dy * dy + dz * dz + dw * dw;
  }
#pragma unroll
  for (int m = 1; m < 64; m <<= 1) vs += __shfl_xor(vs, m, 64);
  const float inv = rsqrtf(vs * (1.f / 1024.f) + 1e-5f);
#pragma unroll
  for (int i = 0; i < 4; ++i) {
    const int col = l * 16 + i * 4;
    const float4 gg = *(const float4*)(g + col);
    const float4 bb = *(const float4*)(b + col);
    u16x4 o;
    o[0] = f2b((v[i].x - mean) * inv * gg.x + bb.x);
    o[1] = f2b((v[i].y - mean) * inv * gg.y + bb.y);
    o[2] = f2b((v[i].z - mean) * inv * gg.z + bb.z);
    o[3] = f2b((v[i].w - mean) * inv * gg.w + bb.w);
    *(u16x4*)(out + (size_t)row * 1024 + col) = o;
  }
}

// Transpose per-head V into Vt[b][h][d=64][t=512] for vectorized PV loads.
__global__ void vt_kernel(const unsigned short* __restrict__ Vsrc, int vsd,
                          unsigned short* __restrict__ Vt) {
  __shared__ alignas(16) unsigned short t[64][72];
  const int tt = blockIdx.x;     // token tile 0..7
  const int h  = blockIdx.y;
  const int b  = blockIdx.z;
  const int tid = threadIdx.x;
  const int r  = tid >> 2;       // token in tile (0..63)
  const int ch = tid & 3;        // 16-elem d chunk (0..3)
  const unsigned short* src =
      Vsrc + (size_t)(b * 512 + tt * 64 + r) * vsd + (size_t)h * 64 + ch * 16;
  const bf16x8 v0 = *(const bf16x8*)src;
  const bf16x8 v1 = *(const bf16x8*)(src + 8);
#pragma unroll
  for (int j = 0; j < 8; ++j) {
    t[ch * 16 + j][r]     = (unsigned short)v0[j];
    t[ch * 16 + 8 + j][r] = (unsigned short)v1[j];
  }
  __syncthreads();
  const int d  = tid >> 2;       // d (0..63)
  const int tp = tid & 3;        // token sub-chunk (16 tokens)
  unsigned short* dst = Vt + (((size_t)(b * 16 + h) * 64 + d) * 512) + tt * 64 + tp * 16;
  *(bf16x8*)dst       = *(const bf16x8*)&t[d][tp * 16];
  *(bf16x8*)(dst + 8) = *(const bf16x8*)&t[d][tp * 16 + 8];
}

// ---------------- GEMM: C = A(bf16 MxK) * W(bf16 NxK)^T + bias ----------------
// BM=128, BN in {64,128}, BK=64; 4 waves (2x2), wave tile 64 x BN/2.
// Double-buffered LDS, one __syncthreads per K-step, stage after barrier.
// T2 XOR-swizzle via pre-swizzled global source. XCD swizzle + bx-MAJOR tile
// decomposition: each XCD's contiguous chunk is a tall column stripe, so its
// B-panel (<=1.5 MB) stays resident in the 4 MB per-XCD L2 across K-steps.

enum { EPI_BF16 = 0, EPI_RELU_BF16 = 1, EPI_RES = 2, EPI_RES2 = 3 };

template<int EPI, int BM, int BN>
__global__ void gemm_bt(const unsigned short* __restrict__ A,
                        const unsigned short* __restrict__ Bw,
                        const float* __restrict__ bias,
                        int N, int K,
                        void* out0, const float* res, float* out1) {
  constexpr int MI = BM / 32;          // frag rows per wave
  constexpr int NJ = BN / 32;          // frag cols per wave
  constexpr int NMB = 4096 / BM;       // M is always 4096
  __shared__ alignas(16) unsigned short As[2][BM * 64];
  __shared__ alignas(16) unsigned short Bs[2][BN * 64];
  const int tid = threadIdx.x;
  const int lane = tid & 63;
  const int wave = tid >> 6;
  int id = blockIdx.x;
  const int nwg = gridDim.x;
  id = (id & 7) * (nwg >> 3) + (id >> 3);       // XCD swizzle (nwg % 8 == 0)
  const int by = id % NMB;                      // bx-major: XCD chunk = column stripe
  const int bx = id / NMB;
  const int m0 = by * BM;
  const int n0 = bx * BN;
  const int wm = (wave >> 1) * (BM / 2);
  const int wn = (wave & 1) * (BN / 2);

  auto stage = [&](int buf, int kt) {
    const size_t k0 = (size_t)kt * 64;
#pragma unroll
    for (int i = 0; i < MI; ++i) {              // A: BM x 64 = BM*8 chunks
      const int c = tid + 256 * i;
      const int row = c >> 3;
      const int lc = (c & 7) ^ (row & 7);       // pre-swizzled source chunk
      gload16(A + (size_t)(m0 + row) * K + k0 + lc * 8, &As[buf][c * 8]);
    }
#pragma unroll
    for (int i = 0; i < NJ; ++i) {              // B: BN x 64 chunks
      const int c = tid + 256 * i;
      const int row = c >> 3;
      const int lc = (c & 7) ^ (row & 7);
      gload16(Bw + (size_t)(n0 + row) * K + k0 + lc * 8, &Bs[buf][c * 8]);
    }
  };

  f32x4 acc[MI][NJ];
#pragma unroll
  for (int i = 0; i < MI; ++i)
#pragma unroll
    for (int j = 0; j < NJ; ++j) acc[i][j] = f32x4{0.f, 0.f, 0.f, 0.f};

  const int nk = K >> 6;
  stage(0, 0);
  int cur = 0;
  const int ro = lane & 15;
  const int hi = lane >> 4;
  for (int kt = 0; kt < nk; ++kt) {
    __syncthreads();                     // buf[cur] staged & prior reads drained
    if (kt + 1 < nk) stage(cur ^ 1, kt + 1);
    bf16x8 af[MI][2], bf[NJ][2];
#pragma unroll
    for (int i = 0; i < MI; ++i) {
      const int r = wm + i * 16 + ro;
#pragma unroll
      for (int ks = 0; ks < 2; ++ks)
        af[i][ks] = *(const bf16x8*)&As[cur][r * 64 + (((ks << 2) + hi) ^ (r & 7)) * 8];
    }
#pragma unroll
    for (int j = 0; j < NJ; ++j) {
      const int r = wn + j * 16 + ro;
#pragma unroll
      for (int ks = 0; ks < 2; ++ks)
        bf[j][ks] = *(const bf16x8*)&Bs[cur][r * 64 + (((ks << 2) + hi) ^ (r & 7)) * 8];
    }
#pragma unroll
    for (int ks = 0; ks < 2; ++ks)
#pragma unroll
      for (int i = 0; i < MI; ++i)
#pragma unroll
        for (int j = 0; j < NJ; ++j)
          acc[i][j] = __builtin_amdgcn_mfma_f32_16x16x32_bf16(af[i][ks], bf[j][ks], acc[i][j], 0, 0, 0);
    cur ^= 1;
  }

  const int r4 = hi * 4;
#pragma unroll
  for (int i = 0; i < MI; ++i) {
#pragma unroll
    for (int j = 0; j < NJ; ++j) {
      const int cg = n0 + wn + j * 16 + ro;
      const float bv = bias[cg];
#pragma unroll
      for (int q = 0; q < 4; ++q) {
        const int rg = m0 + wm + i * 16 + r4 + q;
        const size_t idx = (size_t)rg * N + cg;
        const float v = acc[i][j][q] + bv;
        if (EPI == EPI_BF16) {
          ((unsigned short*)out0)[idx] = f2b(v);
        } else if (EPI == EPI_RELU_BF16) {
          ((unsigned short*)out0)[idx] = f2b(fmaxf(v, 0.f));
        } else if (EPI == EPI_RES) {
          ((float*)out0)[idx] = res[idx] + v;        // out may alias res
        } else {                                      // EPI_RES2
          const float r = res[idx];
          ((float*)out0)[idx] = v;                    // c = val
          out1[idx] = r + v;                          // x = x + val (out1 aliases res)
        }
      }
    }
  }
}

// ---------------- fused flash attention ----------------
// 1 wave per block; block = (qt, h, b); q-tile 32 rows, k-tiles of 64.
// Q/K pre-offset to head-col 0 (row strides passed); V in Vt[b][h][64][512].

template<bool CAUSAL>
__global__ __launch_bounds__(64) void attn_kernel(
    const unsigned short* __restrict__ Qg, int qs,
    const unsigned short* __restrict__ Kg, int ksd,
    const unsigned short* __restrict__ Vt,
    unsigned short* __restrict__ Og) {
  __shared__ alignas(16) unsigned short Pl[32 * 64];
  const int qt = blockIdx.x;       // 0..15 (32-row tiles)
  const int h  = blockIdx.y;
  const int b  = blockIdx.z;
  const int lane = threadIdx.x;
  const int ro = lane & 15;
  const int hi = lane >> 4;
  const size_t qbase = (size_t)b * 512 * qs  + (size_t)h * 64;
  const size_t kbase = (size_t)b * 512 * ksd + (size_t)h * 64;
  const size_t vbase = ((size_t)(b * 16 + h)) * 64 * 512;
  const size_t obase = (size_t)b * 512 * 1024 + (size_t)h * 64;

  bf16x8 qf[2][2];
#pragma unroll
  for (int mi = 0; mi < 2; ++mi)
#pragma unroll
    for (int ks = 0; ks < 2; ++ks)
      qf[mi][ks] = *(const bf16x8*)&Qg[qbase + (size_t)(qt * 32 + mi * 16 + ro) * qs + ks * 32 + hi * 8];

  f32x4 o[2][4];
  float mrun[2][4], lrun[2][4];
#pragma unroll
  for (int mi = 0; mi < 2; ++mi) {
#pragma unroll
    for (int di = 0; di < 4; ++di) o[mi][di] = f32x4{0.f, 0.f, 0.f, 0.f};
#pragma unroll
    for (int q = 0; q < 4; ++q) { mrun[mi][q] = -1e30f; lrun[mi][q] = 0.f; }
  }

  const int ktmax = CAUSAL ? (qt >> 1) : 7;
  for (int kt = 0; kt <= ktmax; ++kt) {
    bf16x8 kf[4][2];
#pragma unroll
    for (int ni = 0; ni < 4; ++ni)
#pragma unroll
      for (int ks = 0; ks < 2; ++ks)
        kf[ni][ks] = *(const bf16x8*)&Kg[kbase + (size_t)(kt * 64 + ni * 16 + ro) * ksd + ks * 32 + hi * 8];

    f32x4 s[2][4];
#pragma unroll
    for (int mi = 0; mi < 2; ++mi)
#pragma unroll
      for (int ni = 0; ni < 4; ++ni) s[mi][ni] = f32x4{0.f, 0.f, 0.f, 0.f};
#pragma unroll
    for (int ks = 0; ks < 2; ++ks)
#pragma unroll
      for (int mi = 0; mi < 2; ++mi)
#pragma unroll
        for (int ni = 0; ni < 4; ++ni)
          s[mi][ni] = __builtin_amdgcn_mfma_f32_16x16x32_bf16(qf[mi][ks], kf[ni][ks], s[mi][ni], 0, 0, 0);

    // scale + causal mask (only the last k-tile can cross the diagonal)
#pragma unroll
    for (int mi = 0; mi < 2; ++mi)
#pragma unroll
      for (int ni = 0; ni < 4; ++ni)
#pragma unroll
        for (int q = 0; q < 4; ++q) {
          float e = s[mi][ni][q] * 0.125f;
          if (CAUSAL && kt == ktmax &&
              (kt * 64 + ni * 16 + ro) > (qt * 32 + mi * 16 + hi * 4 + q)) e = -1e9f;
          s[mi][ni][q] = e;
        }

    // online softmax
    float fac[2][4];
#pragma unroll
    for (int mi = 0; mi < 2; ++mi)
#pragma unroll
      for (int q = 0; q < 4; ++q) {
        float rm = s[mi][0][q];
#pragma unroll
        for (int ni = 1; ni < 4; ++ni) rm = fmaxf(rm, s[mi][ni][q]);
        rm = wred_max16(rm);
        const float mn = fmaxf(mrun[mi][q], rm);
        fac[mi][q] = __expf(mrun[mi][q] - mn);
        mrun[mi][q] = mn;
      }
#pragma unroll
    for (int mi = 0; mi < 2; ++mi)
#pragma unroll
      for (int q = 0; q < 4; ++q) {
        float rs = 0.f;
#pragma unroll
        for (int ni = 0; ni < 4; ++ni) {
          const float pv = __expf(s[mi][ni][q] - mrun[mi][q]);
          s[mi][ni][q] = pv;
          rs += pv;
        }
        rs = wred_sum16(rs);
        lrun[mi][q] = lrun[mi][q] * fac[mi][q] + rs;
      }
#pragma unroll
    for (int mi = 0; mi < 2; ++mi)
#pragma unroll
      for (int di = 0; di < 4; ++di)
#pragma unroll
        for (int q = 0; q < 4; ++q) o[mi][di][q] *= fac[mi][q];

    // P -> LDS (XOR-swizzled chunks), read back as A-fragments
#pragma unroll
    for (int mi = 0; mi < 2; ++mi)
#pragma unroll
      for (int ni = 0; ni < 4; ++ni)
#pragma unroll
        for (int q = 0; q < 4; ++q) {
          const int row = mi * 16 + hi * 4 + q;
          const int col = ni * 16 + ro;
          const int sc  = ((col >> 3) ^ (row & 7)) * 8 + (col & 7);
          Pl[row * 64 + sc] = f2b(s[mi][ni][q]);
        }

    bf16x8 pa[2][2];
#pragma unroll
    for (int mi = 0; mi < 2; ++mi)
#pragma unroll
      for (int ks = 0; ks < 2; ++ks) {
        const int row = mi * 16 + ro;
        pa[mi][ks] = *(const bf16x8*)&Pl[row * 64 + (((ks << 2) + hi) ^ (row & 7)) * 8];
      }

#pragma unroll
    for (int di = 0; di < 4; ++di)
#pragma unroll
      for (int ks = 0; ks < 2; ++ks) {
        const bf16x8 vf = *(const bf16x8*)&Vt[vbase + (size_t)(di * 16 + ro) * 512 + kt * 64 + ks * 32 + hi * 8];
#pragma unroll
        for (int mi = 0; mi < 2; ++mi)
          o[mi][di] = __builtin_amdgcn_mfma_f32_16x16x32_bf16(pa[mi][ks], vf, o[mi][di], 0, 0, 0);
      }
  }

#pragma unroll
  for (int mi = 0; mi < 2; ++mi)
#pragma unroll
    for (int di = 0; di < 4; ++di)
#pragma unroll
      for (int q = 0; q < 4; ++q) {
        const float val = o[mi][di][q] / lrun[mi][q];
        Og[obase + (size_t)(qt * 32 + mi * 16 + hi * 4 + q) * 1024 + di * 16 + ro] = f2b(val);
      }
}

// ---------------- host orchestration ----------------

extern "C" void kernel_launch(void* const* d_in, const int* in_sizes, int n_in,
                              void* d_out, int out_size, void* d_ws, size_t ws_size,
                              hipStream_t stream) {
  (void)in_sizes; (void)n_in; (void)out_size; (void)ws_size;
  const int*   dec = (const int*)d_in[0];
  const float* enc = (const float*)d_in[2];
  const float* emb = (const float*)d_in[4];
  const float* pe  = (const float*)d_in[5];
  const float* wq  = (const float*)d_in[6];
  const float* bq  = (const float*)d_in[7];
  const float* wk  = (const float*)d_in[8];
  const float* bk  = (const float*)d_in[9];
  const float* wv  = (const float*)d_in[10];
  const float* bv  = (const float*)d_in[11];
  const float* wo  = (const float*)d_in[12];
  const float* bo  = (const float*)d_in[13];
  const float* w1  = (const float*)d_in[14];
  const float* b1  = (const float*)d_in[15];
  const float* w2  = (const float*)d_in[16];
  const float* b2  = (const float*)d_in[17];
  const float* lng = (const float*)d_in[18];
  const float* lnb = (const float*)d_in[19];

  const size_t SZ_ACT = 4194304ull;     // 4096*1024

  char* p = (char*)d_ws;
  auto alloc = [&](size_t bytes) { char* r = p; p += (bytes + 255) & ~(size_t)255; return r; };
  unsigned short* qkvw  = (unsigned short*)alloc(3ull * 3 * 1048576 * 2);  // [L][3072][1024]
  unsigned short* kvw   = (unsigned short*)alloc(3ull * 2 * 1048576 * 2);  // [L][2048][1024]
  unsigned short* wqxb  = (unsigned short*)alloc(3ull * 1048576 * 2);      // [L][1024][1024]
  unsigned short* Wob   = (unsigned short*)alloc(6291456ull * 2);          // [L][2][1024][1024]
  unsigned short* W1b   = (unsigned short*)alloc(12582912ull * 2);
  unsigned short* W2b   = (unsigned short*)alloc(12582912ull * 2);
  unsigned short* encb  = (unsigned short*)alloc(SZ_ACT * 2);
  float*          x     = (float*)alloc(SZ_ACT * 4);
  float*          c     = (float*)alloc(SZ_ACT * 4);
  unsigned short* hb    = (unsigned short*)alloc(SZ_ACT * 2);
  unsigned short* qkvb  = (unsigned short*)alloc(4096ull * 3072 * 2);
  unsigned short* kvb   = (unsigned short*)alloc(4096ull * 2048 * 2);
  unsigned short* qb    = (unsigned short*)alloc(SZ_ACT * 2);
  unsigned short* vtb   = (unsigned short*)alloc(SZ_ACT * 2);              // [B][H][64][512]
  unsigned short* mid   = (unsigned short*)alloc(4096ull * 4096 * 2);
  float*          qkvbias = (float*)alloc(3ull * 3072 * 4);
  float*          kvbias  = (float*)alloc(3ull * 2048 * 4);

  cvt_kernel<<<2048, 256, 0, stream>>>(wo, Wob, 1572864);
  cvt_kernel<<<2048, 256, 0, stream>>>(w1, W1b, 3145728);
  cvt_kernel<<<2048, 256, 0, stream>>>(w2, W2b, 3145728);
  cvt_kernel<<<2048, 256, 0, stream>>>(enc, encb, 1048576);
  pack_w<<<dim3(1024, 3, 3), 256, 0, stream>>>(wq, wk, wv, 0, qkvw, 3);
  pack_w<<<dim3(1024, 2, 3), 256, 0, stream>>>(wk, wv, wv, 1, kvw, 2);
  pack_w<<<dim3(1024, 1, 3), 256, 0, stream>>>(wq, wq, wq, 1, wqxb, 1);
  pack_bias<<<dim3(3, 3), 256, 0, stream>>>(bq, bk, bv, 0, qkvbias, 3);
  pack_bias<<<dim3(2, 3), 256, 0, stream>>>(bk, bv, bv, 1, kvbias, 2);
  embed_kernel<<<4096, 256, 0, stream>>>(dec, emb, pe, x);

  const dim3 gAttn(16, 16, 8);
  const dim3 gVt(8, 16, 8);

  for (int l = 0; l < 3; ++l) {
    const float* g0 = lng + (l * 3 + 0) * 1024; const float* e0 = lnb + (l * 3 + 0) * 1024;
    const float* g1 = lng + (l * 3 + 1) * 1024; const float* e1 = lnb + (l * 3 + 1) * 1024;
    const float* g2 = lng + (l * 3 + 2) * 1024; const float* e2 = lnb + (l * 3 + 2) * 1024;

    // ---- self-attention sublayer ----
    ln_kernel<<<4096, 64, 0, stream>>>(x, g0, e0, hb);
    gemm_bt<EPI_BF16, 128, 128><<<32 * 24, 256, 0, stream>>>(hb, qkvw + (size_t)l * 3 * 1048576,
        qkvbias + l * 3072, 3072, 1024, qkvb, nullptr, nullptr);
    vt_kernel<<<gVt, 256, 0, stream>>>(qkvb + 2048, 3072, vtb);
    attn_kernel<true><<<gAttn, 64, 0, stream>>>(qkvb, 3072, qkvb + 1024, 3072, vtb, hb);
    gemm_bt<EPI_RES, 128, 64><<<32 * 16, 256, 0, stream>>>(hb, Wob + (size_t)(l * 2) * 1048576,
        bo + (l * 2) * 1024, 1024, 1024, x, x, nullptr);

    // ---- cross-attention sublayer ----
    ln_kernel<<<4096, 64, 0, stream>>>(x, g1, e1, hb);
    gemm_bt<EPI_BF16, 128, 64><<<32 * 16, 256, 0, stream>>>(hb, wqxb + (size_t)l * 1048576,
        bq + (l * 2 + 1) * 1024, 1024, 1024, qb, nullptr, nullptr);
    gemm_bt<EPI_BF16, 128, 128><<<32 * 16, 256, 0, stream>>>(encb, kvw + (size_t)l * 2 * 1048576,
        kvbias + l * 2048, 2048, 1024, kvb, nullptr, nullptr);
    vt_kernel<<<gVt, 256, 0, stream>>>(kvb + 1024, 2048, vtb);
    attn_kernel<false><<<gAttn, 64, 0, stream>>>(qb, 1024, kvb, 2048, vtb, hb);
    gemm_bt<EPI_RES2, 128, 64><<<32 * 16, 256, 0, stream>>>(hb, Wob + (size_t)(l * 2 + 1) * 1048576,
        bo + (l * 2 + 1) * 1024, 1024, 1024, c, x, x);

    // ---- FFN sublayer (residual is c, per reference quirk) ----
    ln_kernel<<<4096, 64, 0, stream>>>(x, g2, e2, hb);
    gemm_bt<EPI_RELU_BF16, 128, 128><<<32 * 32, 256, 0, stream>>>(hb, W1b + (size_t)l * 4194304,
        b1 + l * 4096, 4096, 1024, mid, nullptr, nullptr);
    float* xout = (l == 2) ? (float*)d_out : x;
    gemm_bt<EPI_RES, 128, 64><<<32 * 16, 256, 0, stream>>>(mid, W2b + (size_t)l * 4194304,
        b2 + l * 1024, 1024, 4096, xout, c, nullptr);
  }
}

// Round 10
// 1182.571 us; speedup vs baseline: 1.1376x; 1.1376x over previous
//
#include <hip/hip_runtime.h>
#include <hip/hip_bf16.h>

using bf16x8 = __attribute__((ext_vector_type(8))) short;
using f32x4  = __attribute__((ext_vector_type(4))) float;
using u16x4  = __attribute__((ext_vector_type(4))) unsigned short;

#define DEVI static __device__ __forceinline__

DEVI unsigned short f2b(float f) {           // f32 -> bf16 RNE
  unsigned int u = __float_as_uint(f);
  u += 0x7FFFu + ((u >> 16) & 1u);
  return (unsigned short)(u >> 16);
}

DEVI void gload16(const unsigned short* g, unsigned short* l) {
  __builtin_amdgcn_global_load_lds(
      (const __attribute__((address_space(1))) unsigned int*)g,
      (__attribute__((address_space(3))) unsigned int*)l, 16, 0, 0);
}

DEVI float wred_max16(float v) {
#pragma unroll
  for (int m = 1; m < 16; m <<= 1) v = fmaxf(v, __shfl_xor(v, m, 64));
  return v;
}
DEVI float wred_sum16(float v) {
#pragma unroll
  for (int m = 1; m < 16; m <<= 1) v += __shfl_xor(v, m, 64);
  return v;
}

// ---------------- elementwise / pack kernels ----------------

__global__ void cvt_kernel(const float* __restrict__ in,
                           unsigned short* __restrict__ out, int n4) {
  int i = blockIdx.x * blockDim.x + threadIdx.x;
  const int stride = gridDim.x * blockDim.x;
  for (; i < n4; i += stride) {
    const float4 v = ((const float4*)in)[i];
    u16x4 o;
    o[0] = f2b(v.x); o[1] = f2b(v.y); o[2] = f2b(v.z); o[3] = f2b(v.w);
    ((u16x4*)out)[i] = o;
  }
}

// Pack rows of up to 3 source weight tensors ([L][2][1024][1024] f32, sub-slot
// `sub`) into a fused bf16 buffer dst[l][nm*1024][1024].
__global__ void pack_w(const float* __restrict__ s0,
                       const float* __restrict__ s1,
                       const float* __restrict__ s2,
                       int sub, unsigned short* __restrict__ dst, int nm) {
  const int r = blockIdx.x;      // row 0..1023
  const int m = blockIdx.y;      // matrix slot
  const int l = blockIdx.z;      // layer
  const float* src = (m == 0 ? s0 : m == 1 ? s1 : s2)
                   + (size_t)(l * 2 + sub) * 1048576 + (size_t)r * 1024;
  unsigned short* d = dst + ((size_t)(l * nm + m) * 1024 + r) * 1024;
  const int col = threadIdx.x * 4;
  const float4 v = *(const float4*)(src + col);
  u16x4 o;
  o[0] = f2b(v.x); o[1] = f2b(v.y); o[2] = f2b(v.z); o[3] = f2b(v.w);
  *(u16x4*)(d + col) = o;
}

__global__ void pack_bias(const float* __restrict__ s0,
                          const float* __restrict__ s1,
                          const float* __restrict__ s2,
                          int sub, float* __restrict__ dst, int nm) {
  const int m = blockIdx.x, l = blockIdx.y;
  const float* src = (m == 0 ? s0 : m == 1 ? s1 : s2) + (size_t)(l * 2 + sub) * 1024;
  float* d = dst + ((size_t)l * nm + m) * 1024;
  const int i = threadIdx.x * 4;
  *(float4*)(d + i) = *(const float4*)(src + i);
}

__global__ void embed_kernel(const int* __restrict__ ids,
                             const float* __restrict__ emb,
                             const float* __restrict__ pe,
                             float* __restrict__ x) {
  const int row = blockIdx.x;           // b*512 + t
  const int t = row & 511;
  const int col = threadIdx.x * 4;      // 256 threads
  const int id = ids[row];
  const float4 e = *(const float4*)(emb + (size_t)id * 1024 + col);
  const float4 p = *(const float4*)(pe + (size_t)t * 1024 + col);
  float4 o;
  o.x = e.x * 32.f + p.x; o.y = e.y * 32.f + p.y;
  o.z = e.z * 32.f + p.z; o.w = e.w * 32.f + p.w;
  *(float4*)(x + (size_t)row * 1024 + col) = o;
}

__global__ void ln_kernel(const float* __restrict__ x,
                          const float* __restrict__ g,
                          const float* __restrict__ b,
                          unsigned short* __restrict__ out) {
  const int row = blockIdx.x;
  const int l = threadIdx.x;            // 64 lanes, 16 elems each
  const float4* xr = (const float4*)(x + (size_t)row * 1024);
  float4 v[4];
  float s = 0.f;
#pragma unroll
  for (int i = 0; i < 4; ++i) {
    v[i] = xr[l * 4 + i];
    s += v[i].x + v[i].y + v[i].z + v[i].w;
  }
#pragma unroll
  for (int m = 1; m < 64; m <<= 1) s += __shfl_xor(s, m, 64);
  const float mean = s * (1.f / 1024.f);
  float vs = 0.f;
#pragma unroll
  for (int i = 0; i < 4; ++i) {
    float dx = v[i].x - mean, dy = v[i].y - mean, dz = v[i].z - mean, dw = v[i].w - mean;
    vs += dx * dx + dy * dy + dz * dz + dw * dw;
  }
#pragma unroll
  for (int m = 1; m < 64; m <<= 1) vs += __shfl_xor(vs, m, 64);
  const float inv = rsqrtf(vs * (1.f / 1024.f) + 1e-5f);
#pragma unroll
  for (int i = 0; i < 4; ++i) {
    const int col = l * 16 + i * 4;
    const float4 gg = *(const float4*)(g + col);
    const float4 bb = *(const float4*)(b + col);
    u16x4 o;
    o[0] = f2b((v[i].x - mean) * inv * gg.x + bb.x);
    o[1] = f2b((v[i].y - mean) * inv * gg.y + bb.y);
    o[2] = f2b((v[i].z - mean) * inv * gg.z + bb.z);
    o[3] = f2b((v[i].w - mean) * inv * gg.w + bb.w);
    *(u16x4*)(out + (size_t)row * 1024 + col) = o;
  }
}

// Transpose per-head V into Vt[b][h][d=64][t=512] for vectorized PV loads.
__global__ void vt_kernel(const unsigned short* __restrict__ Vsrc, int vsd,
                          unsigned short* __restrict__ Vt) {
  __shared__ alignas(16) unsigned short t[64][72];
  const int tt = blockIdx.x;     // token tile 0..7
  const int h  = blockIdx.y;
  const int b  = blockIdx.z;
  const int tid = threadIdx.x;
  const int r  = tid >> 2;       // token in tile (0..63)
  const int ch = tid & 3;        // 16-elem d chunk (0..3)
  const unsigned short* src =
      Vsrc + (size_t)(b * 512 + tt * 64 + r) * vsd + (size_t)h * 64 + ch * 16;
  const bf16x8 v0 = *(const bf16x8*)src;
  const bf16x8 v1 = *(const bf16x8*)(src + 8);
#pragma unroll
  for (int j = 0; j < 8; ++j) {
    t[ch * 16 + j][r]     = (unsigned short)v0[j];
    t[ch * 16 + 8 + j][r] = (unsigned short)v1[j];
  }
  __syncthreads();
  const int d  = tid >> 2;       // d (0..63)
  const int tp = tid & 3;        // token sub-chunk (16 tokens)
  unsigned short* dst = Vt + (((size_t)(b * 16 + h) * 64 + d) * 512) + tt * 64 + tp * 16;
  *(bf16x8*)dst       = *(const bf16x8*)&t[d][tp * 16];
  *(bf16x8*)(dst + 8) = *(const bf16x8*)&t[d][tp * 16 + 8];
}

// ------------- fat GEMM: 256x128 tile, 8 waves, 3-slot LDS ring -------------
// C = A(4096xK=1024) * W(Nx1024)^T + bias, bf16 out (optional relu).
// BK=64; slot = kt mod 3 (static via x3-unrolled loop, distinct __shared__
// arrays). Per ktile: vmcnt(6) -> barrier -> stage kt+2 -> 20 ds_read_b128
// (XOR-swizzled, conflict-free) -> 32 MFMA under setprio. Loads stay 2 ktiles
// in flight across barriers (T3/T4); drain to 0 only at the final ktile.

template<int EPI>  // 0 = bf16, 1 = relu+bf16
__global__ __launch_bounds__(512, 2) void gemm256(
    const unsigned short* __restrict__ A,
    const unsigned short* __restrict__ Bw,
    const float* __restrict__ bias,
    int N, unsigned short* __restrict__ out0) {
  constexpr int K = 1024, NK = 16;
  __shared__ alignas(16) unsigned short As0[256 * 64];
  __shared__ alignas(16) unsigned short As1[256 * 64];
  __shared__ alignas(16) unsigned short As2[256 * 64];
  __shared__ alignas(16) unsigned short Bs0[128 * 64];
  __shared__ alignas(16) unsigned short Bs1[128 * 64];
  __shared__ alignas(16) unsigned short Bs2[128 * 64];
  const int tid = threadIdx.x;
  const int lane = tid & 63;
  const int wave = tid >> 6;
  const int wr = wave >> 2;       // 0..1 (row half)
  const int wc = wave & 3;        // 0..3 (col quarter)
  int id = blockIdx.x;
  const int nwg = gridDim.x;
  id = (id & 7) * (nwg >> 3) + (id >> 3);     // XCD swizzle (nwg % 8 == 0)
  const int nn = N >> 7;
  const int bx = id % nn;
  const int by = id / nn;
  const int m0 = by * 256;
  const int n0 = bx * 128;
  const int ro = lane & 15;
  const int hi = lane >> 4;

  auto stageA = [&](unsigned short* dst, int kt) {
    const size_t k0 = (size_t)kt * 64;
#pragma unroll
    for (int i = 0; i < 4; ++i) {             // 256x64 = 2048 chunks
      const int c = tid + 512 * i;
      const int row = c >> 3;
      const int lc = (c & 7) ^ (row & 7);
      gload16(A + (size_t)(m0 + row) * K + k0 + lc * 8, dst + c * 8);
    }
  };
  auto stageB = [&](unsigned short* dst, int kt) {
    const size_t k0 = (size_t)kt * 64;
#pragma unroll
    for (int i = 0; i < 2; ++i) {             // 128x64 = 1024 chunks
      const int c = tid + 512 * i;
      const int row = c >> 3;
      const int lc = (c & 7) ^ (row & 7);
      gload16(Bw + (size_t)(n0 + row) * K + k0 + lc * 8, dst + c * 8);
    }
  };

  f32x4 acc[8][2];
#pragma unroll
  for (int i = 0; i < 8; ++i)
#pragma unroll
    for (int j = 0; j < 2; ++j) acc[i][j] = f32x4{0.f, 0.f, 0.f, 0.f};

  stageA(As0, 0); stageB(Bs0, 0);     // 6 loads
  stageA(As1, 1); stageB(Bs1, 1);     // 6 loads (12 outstanding)

  auto body = [&](int kt, const unsigned short* Ac, const unsigned short* Bc,
                  unsigned short* An, unsigned short* Bn, bool last) {
    if (last) asm volatile("s_waitcnt vmcnt(0)" ::: "memory");
    else      asm volatile("s_waitcnt vmcnt(6)" ::: "memory");
    __builtin_amdgcn_s_barrier();             // ktile kt landed for ALL waves;
                                              // slot (kt+2)%3 free to overwrite
    if (kt + 2 < NK) { stageA(An, kt + 2); stageB(Bn, kt + 2); }
    bf16x8 af[8][2], bf[2][2];
#pragma unroll
    for (int mi = 0; mi < 8; ++mi) {
      const int r = wr * 128 + mi * 16 + ro;
#pragma unroll
      for (int ks = 0; ks < 2; ++ks)
        af[mi][ks] = *(const bf16x8*)&Ac[r * 64 + (((ks << 2) + hi) ^ (r & 7)) * 8];
    }
#pragma unroll
    for (int nj = 0; nj < 2; ++nj) {
      const int r = wc * 32 + nj * 16 + ro;
#pragma unroll
      for (int ks = 0; ks < 2; ++ks)
        bf[nj][ks] = *(const bf16x8*)&Bc[r * 64 + (((ks << 2) + hi) ^ (r & 7)) * 8];
    }
    __builtin_amdgcn_s_setprio(1);
#pragma unroll
    for (int ks = 0; ks < 2; ++ks)
#pragma unroll
      for (int mi = 0; mi < 8; ++mi)
#pragma unroll
        for (int nj = 0; nj < 2; ++nj)
          acc[mi][nj] = __builtin_amdgcn_mfma_f32_16x16x32_bf16(af[mi][ks], bf[nj][ks], acc[mi][nj], 0, 0, 0);
    __builtin_amdgcn_s_setprio(0);
  };

  for (int base = 0; base < 15; base += 3) {  // ktiles 0..14, slots 0/1/2
    body(base,     As0, Bs0, As2, Bs2, false);
    body(base + 1, As1, Bs1, As0, Bs0, false);
    body(base + 2, As2, Bs2, As1, Bs1, false);
  }
  body(15, As0, Bs0, As1, Bs1, true);         // kt=15: slot 0, no stage, drain

  const int r4 = hi * 4;
#pragma unroll
  for (int mi = 0; mi < 8; ++mi) {
#pragma unroll
    for (int nj = 0; nj < 2; ++nj) {
      const int cg = n0 + wc * 32 + nj * 16 + ro;
      const float bv = bias[cg];
#pragma unroll
      for (int q = 0; q < 4; ++q) {
        const int rg = m0 + wr * 128 + mi * 16 + r4 + q;
        const float v = acc[mi][nj][q] + bv;
        out0[(size_t)rg * N + cg] = f2b(EPI == 1 ? fmaxf(v, 0.f) : v);
      }
    }
  }
}

// ---------------- skinny GEMM (R7 structure, BM=128, BN=64) ----------------

enum { EPI_BF16 = 0, EPI_RELU_BF16 = 1, EPI_RES = 2, EPI_RES2 = 3 };

template<int EPI, int BM, int BN>
__global__ void gemm_bt(const unsigned short* __restrict__ A,
                        const unsigned short* __restrict__ Bw,
                        const float* __restrict__ bias,
                        int N, int K, int nn,
                        void* out0, const float* res, float* out1) {
  constexpr int MI = BM / 32;
  constexpr int NJ = BN / 32;
  __shared__ alignas(16) unsigned short As[2][BM * 64];
  __shared__ alignas(16) unsigned short Bs[2][BN * 64];
  const int tid = threadIdx.x;
  const int lane = tid & 63;
  const int wave = tid >> 6;
  int id = blockIdx.x;
  const int nwg = gridDim.x;
  id = (id & 7) * (nwg >> 3) + (id >> 3);
  const int bx = id % nn;
  const int by = id / nn;
  const int m0 = by * BM;
  const int n0 = bx * BN;
  const int wm = (wave >> 1) * (BM / 2);
  const int wn = (wave & 1) * (BN / 2);

  auto stage = [&](int buf, int kt) {
    const size_t k0 = (size_t)kt * 64;
#pragma unroll
    for (int i = 0; i < MI; ++i) {
      const int c = tid + 256 * i;
      const int row = c >> 3;
      const int lc = (c & 7) ^ (row & 7);
      gload16(A + (size_t)(m0 + row) * K + k0 + lc * 8, &As[buf][c * 8]);
    }
#pragma unroll
    for (int i = 0; i < NJ; ++i) {
      const int c = tid + 256 * i;
      const int row = c >> 3;
      const int lc = (c & 7) ^ (row & 7);
      gload16(Bw + (size_t)(n0 + row) * K + k0 + lc * 8, &Bs[buf][c * 8]);
    }
  };

  f32x4 acc[MI][NJ];
#pragma unroll
  for (int i = 0; i < MI; ++i)
#pragma unroll
    for (int j = 0; j < NJ; ++j) acc[i][j] = f32x4{0.f, 0.f, 0.f, 0.f};

  const int nk = K >> 6;
  stage(0, 0);
  int cur = 0;
  const int ro = lane & 15;
  const int hi = lane >> 4;
  for (int kt = 0; kt < nk; ++kt) {
    __syncthreads();
    if (kt + 1 < nk) stage(cur ^ 1, kt + 1);
    bf16x8 af[MI][2], bf[NJ][2];
#pragma unroll
    for (int i = 0; i < MI; ++i) {
      const int r = wm + i * 16 + ro;
#pragma unroll
      for (int ks = 0; ks < 2; ++ks)
        af[i][ks] = *(const bf16x8*)&As[cur][r * 64 + (((ks << 2) + hi) ^ (r & 7)) * 8];
    }
#pragma unroll
    for (int j = 0; j < NJ; ++j) {
      const int r = wn + j * 16 + ro;
#pragma unroll
      for (int ks = 0; ks < 2; ++ks)
        bf[j][ks] = *(const bf16x8*)&Bs[cur][r * 64 + (((ks << 2) + hi) ^ (r & 7)) * 8];
    }
#pragma unroll
    for (int ks = 0; ks < 2; ++ks)
#pragma unroll
      for (int i = 0; i < MI; ++i)
#pragma unroll
        for (int j = 0; j < NJ; ++j)
          acc[i][j] = __builtin_amdgcn_mfma_f32_16x16x32_bf16(af[i][ks], bf[j][ks], acc[i][j], 0, 0, 0);
    cur ^= 1;
  }

  const int r4 = hi * 4;
#pragma unroll
  for (int i = 0; i < MI; ++i) {
#pragma unroll
    for (int j = 0; j < NJ; ++j) {
      const int cg = n0 + wn + j * 16 + ro;
      const float bv = bias[cg];
#pragma unroll
      for (int q = 0; q < 4; ++q) {
        const int rg = m0 + wm + i * 16 + r4 + q;
        const size_t idx = (size_t)rg * N + cg;
        const float v = acc[i][j][q] + bv;
        if (EPI == EPI_BF16) {
          ((unsigned short*)out0)[idx] = f2b(v);
        } else if (EPI == EPI_RELU_BF16) {
          ((unsigned short*)out0)[idx] = f2b(fmaxf(v, 0.f));
        } else if (EPI == EPI_RES) {
          ((float*)out0)[idx] = res[idx] + v;
        } else {
          const float r = res[idx];
          ((float*)out0)[idx] = v;
          out1[idx] = r + v;
        }
      }
    }
  }
}

// ---------------- fused flash attention ----------------

template<bool CAUSAL>
__global__ __launch_bounds__(64) void attn_kernel(
    const unsigned short* __restrict__ Qg, int qs,
    const unsigned short* __restrict__ Kg, int ksd,
    const unsigned short* __restrict__ Vt,
    unsigned short* __restrict__ Og) {
  __shared__ alignas(16) unsigned short Pl[32 * 64];
  const int qt = blockIdx.x;
  const int h  = blockIdx.y;
  const int b  = blockIdx.z;
  const int lane = threadIdx.x;
  const int ro = lane & 15;
  const int hi = lane >> 4;
  const size_t qbase = (size_t)b * 512 * qs  + (size_t)h * 64;
  const size_t kbase = (size_t)b * 512 * ksd + (size_t)h * 64;
  const size_t vbase = ((size_t)(b * 16 + h)) * 64 * 512;
  const size_t obase = (size_t)b * 512 * 1024 + (size_t)h * 64;

  bf16x8 qf[2][2];
#pragma unroll
  for (int mi = 0; mi < 2; ++mi)
#pragma unroll
    for (int ks = 0; ks < 2; ++ks)
      qf[mi][ks] = *(const bf16x8*)&Qg[qbase + (size_t)(qt * 32 + mi * 16 + ro) * qs + ks * 32 + hi * 8];

  f32x4 o[2][4];
  float mrun[2][4], lrun[2][4];
#pragma unroll
  for (int mi = 0; mi < 2; ++mi) {
#pragma unroll
    for (int di = 0; di < 4; ++di) o[mi][di] = f32x4{0.f, 0.f, 0.f, 0.f};
#pragma unroll
    for (int q = 0; q < 4; ++q) { mrun[mi][q] = -1e30f; lrun[mi][q] = 0.f; }
  }

  const int ktmax = CAUSAL ? (qt >> 1) : 7;
  for (int kt = 0; kt <= ktmax; ++kt) {
    bf16x8 kf[4][2];
#pragma unroll
    for (int ni = 0; ni < 4; ++ni)
#pragma unroll
      for (int ks = 0; ks < 2; ++ks)
        kf[ni][ks] = *(const bf16x8*)&Kg[kbase + (size_t)(kt * 64 + ni * 16 + ro) * ksd + ks * 32 + hi * 8];

    f32x4 s[2][4];
#pragma unroll
    for (int mi = 0; mi < 2; ++mi)
#pragma unroll
      for (int ni = 0; ni < 4; ++ni) s[mi][ni] = f32x4{0.f, 0.f, 0.f, 0.f};
#pragma unroll
    for (int ks = 0; ks < 2; ++ks)
#pragma unroll
      for (int mi = 0; mi < 2; ++mi)
#pragma unroll
        for (int ni = 0; ni < 4; ++ni)
          s[mi][ni] = __builtin_amdgcn_mfma_f32_16x16x32_bf16(qf[mi][ks], kf[ni][ks], s[mi][ni], 0, 0, 0);

#pragma unroll
    for (int mi = 0; mi < 2; ++mi)
#pragma unroll
      for (int ni = 0; ni < 4; ++ni)
#pragma unroll
        for (int q = 0; q < 4; ++q) {
          float e = s[mi][ni][q] * 0.125f;
          if (CAUSAL && kt == ktmax &&
              (kt * 64 + ni * 16 + ro) > (qt * 32 + mi * 16 + hi * 4 + q)) e = -1e9f;
          s[mi][ni][q] = e;
        }

    float fac[2][4];
#pragma unroll
    for (int mi = 0; mi < 2; ++mi)
#pragma unroll
      for (int q = 0; q < 4; ++q) {
        float rm = s[mi][0][q];
#pragma unroll
        for (int ni = 1; ni < 4; ++ni) rm = fmaxf(rm, s[mi][ni][q]);
        rm = wred_max16(rm);
        const float mn = fmaxf(mrun[mi][q], rm);
        fac[mi][q] = __expf(mrun[mi][q] - mn);
        mrun[mi][q] = mn;
      }
#pragma unroll
    for (int mi = 0; mi < 2; ++mi)
#pragma unroll
      for (int q = 0; q < 4; ++q) {
        float rs = 0.f;
#pragma unroll
        for (int ni = 0; ni < 4; ++ni) {
          const float pv = __expf(s[mi][ni][q] - mrun[mi][q]);
          s[mi][ni][q] = pv;
          rs += pv;
        }
        rs = wred_sum16(rs);
        lrun[mi][q] = lrun[mi][q] * fac[mi][q] + rs;
      }
#pragma unroll
    for (int mi = 0; mi < 2; ++mi)
#pragma unroll
      for (int di = 0; di < 4; ++di)
#pragma unroll
        for (int q = 0; q < 4; ++q) o[mi][di][q] *= fac[mi][q];

#pragma unroll
    for (int mi = 0; mi < 2; ++mi)
#pragma unroll
      for (int ni = 0; ni < 4; ++ni)
#pragma unroll
        for (int q = 0; q < 4; ++q) {
          const int row = mi * 16 + hi * 4 + q;
          const int col = ni * 16 + ro;
          const int sc  = ((col >> 3) ^ (row & 7)) * 8 + (col & 7);
          Pl[row * 64 + sc] = f2b(s[mi][ni][q]);
        }

    bf16x8 pa[2][2];
#pragma unroll
    for (int mi = 0; mi < 2; ++mi)
#pragma unroll
      for (int ks = 0; ks < 2; ++ks) {
        const int row = mi * 16 + ro;
        pa[mi][ks] = *(const bf16x8*)&Pl[row * 64 + (((ks << 2) + hi) ^ (row & 7)) * 8];
      }

#pragma unroll
    for (int di = 0; di < 4; ++di)
#pragma unroll
      for (int ks = 0; ks < 2; ++ks) {
        const bf16x8 vf = *(const bf16x8*)&Vt[vbase + (size_t)(di * 16 + ro) * 512 + kt * 64 + ks * 32 + hi * 8];
#pragma unroll
        for (int mi = 0; mi < 2; ++mi)
          o[mi][di] = __builtin_amdgcn_mfma_f32_16x16x32_bf16(pa[mi][ks], vf, o[mi][di], 0, 0, 0);
      }
  }

#pragma unroll
  for (int mi = 0; mi < 2; ++mi)
#pragma unroll
    for (int di = 0; di < 4; ++di)
#pragma unroll
      for (int q = 0; q < 4; ++q) {
        const float val = o[mi][di][q] / lrun[mi][q];
        Og[obase + (size_t)(qt * 32 + mi * 16 + hi * 4 + q) * 1024 + di * 16 + ro] = f2b(val);
      }
}

// ---------------- host orchestration ----------------

extern "C" void kernel_launch(void* const* d_in, const int* in_sizes, int n_in,
                              void* d_out, int out_size, void* d_ws, size_t ws_size,
                              hipStream_t stream) {
  (void)in_sizes; (void)n_in; (void)out_size; (void)ws_size;
  const int*   dec = (const int*)d_in[0];
  const float* enc = (const float*)d_in[2];
  const float* emb = (const float*)d_in[4];
  const float* pe  = (const float*)d_in[5];
  const float* wq  = (const float*)d_in[6];
  const float* bq  = (const float*)d_in[7];
  const float* wk  = (const float*)d_in[8];
  const float* bk  = (const float*)d_in[9];
  const float* wv  = (const float*)d_in[10];
  const float* bv  = (const float*)d_in[11];
  const float* wo  = (const float*)d_in[12];
  const float* bo  = (const float*)d_in[13];
  const float* w1  = (const float*)d_in[14];
  const float* b1  = (const float*)d_in[15];
  const float* w2  = (const float*)d_in[16];
  const float* b2  = (const float*)d_in[17];
  const float* lng = (const float*)d_in[18];
  const float* lnb = (const float*)d_in[19];

  const size_t SZ_ACT = 4194304ull;     // 4096*1024

  char* p = (char*)d_ws;
  auto alloc = [&](size_t bytes) { char* r = p; p += (bytes + 255) & ~(size_t)255; return r; };
  unsigned short* qkvw  = (unsigned short*)alloc(3ull * 3 * 1048576 * 2);  // [L][3072][1024]
  unsigned short* kvw   = (unsigned short*)alloc(3ull * 2 * 1048576 * 2);  // [6144][1024]
  unsigned short* wqxb  = (unsigned short*)alloc(3ull * 1048576 * 2);      // [L][1024][1024]
  unsigned short* Wob   = (unsigned short*)alloc(6291456ull * 2);          // [L][2][1024][1024]
  unsigned short* W1b   = (unsigned short*)alloc(12582912ull * 2);
  unsigned short* W2b   = (unsigned short*)alloc(12582912ull * 2);
  unsigned short* encb  = (unsigned short*)alloc(SZ_ACT * 2);
  float*          x     = (float*)alloc(SZ_ACT * 4);
  float*          c     = (float*)alloc(SZ_ACT * 4);
  unsigned short* hb    = (unsigned short*)alloc(SZ_ACT * 2);
  unsigned short* qkvb  = (unsigned short*)alloc(4096ull * 3072 * 2);
  unsigned short* kvb   = (unsigned short*)alloc(4096ull * 6144 * 2);      // merged 3-layer K/V
  unsigned short* qb    = (unsigned short*)alloc(SZ_ACT * 2);
  unsigned short* vtb   = (unsigned short*)alloc(SZ_ACT * 2);              // [B][H][64][512]
  unsigned short* mid   = (unsigned short*)alloc(4096ull * 4096 * 2);
  float*          qkvbias = (float*)alloc(3ull * 3072 * 4);
  float*          kvbias  = (float*)alloc(3ull * 2048 * 4);

  cvt_kernel<<<2048, 256, 0, stream>>>(wo, Wob, 1572864);
  cvt_kernel<<<2048, 256, 0, stream>>>(w1, W1b, 3145728);
  cvt_kernel<<<2048, 256, 0, stream>>>(w2, W2b, 3145728);
  cvt_kernel<<<2048, 256, 0, stream>>>(enc, encb, 1048576);
  pack_w<<<dim3(1024, 3, 3), 256, 0, stream>>>(wq, wk, wv, 0, qkvw, 3);
  pack_w<<<dim3(1024, 2, 3), 256, 0, stream>>>(wk, wv, wv, 1, kvw, 2);
  pack_w<<<dim3(1024, 1, 3), 256, 0, stream>>>(wq, wq, wq, 1, wqxb, 1);
  pack_bias<<<dim3(3, 3), 256, 0, stream>>>(bq, bk, bv, 0, qkvbias, 3);
  pack_bias<<<dim3(2, 3), 256, 0, stream>>>(bk, bv, bv, 1, kvbias, 2);
  embed_kernel<<<4096, 256, 0, stream>>>(dec, emb, pe, x);

  // merged cross-attn K/V for all 3 layers: [4096][6144]
  gemm256<0><<<48 * 16, 512, 0, stream>>>(encb, kvw, kvbias, 6144, kvb);

  const dim3 gAttn(16, 16, 8);
  const dim3 gVt(8, 16, 8);

  for (int l = 0; l < 3; ++l) {
    const float* g0 = lng + (l * 3 + 0) * 1024; const float* e0 = lnb + (l * 3 + 0) * 1024;
    const float* g1 = lng + (l * 3 + 1) * 1024; const float* e1 = lnb + (l * 3 + 1) * 1024;
    const float* g2 = lng + (l * 3 + 2) * 1024; const float* e2 = lnb + (l * 3 + 2) * 1024;

    // ---- self-attention sublayer ----
    ln_kernel<<<4096, 64, 0, stream>>>(x, g0, e0, hb);
    gemm256<0><<<24 * 16, 512, 0, stream>>>(hb, qkvw + (size_t)l * 3 * 1048576,
        qkvbias + l * 3072, 3072, qkvb);
    vt_kernel<<<gVt, 256, 0, stream>>>(qkvb + 2048, 3072, vtb);
    attn_kernel<true><<<gAttn, 64, 0, stream>>>(qkvb, 3072, qkvb + 1024, 3072, vtb, hb);
    gemm_bt<EPI_RES, 128, 64><<<32 * 16, 256, 0, stream>>>(hb, Wob + (size_t)(l * 2) * 1048576,
        bo + (l * 2) * 1024, 1024, 1024, 16, x, x, nullptr);

    // ---- cross-attention sublayer ----
    ln_kernel<<<4096, 64, 0, stream>>>(x, g1, e1, hb);
    gemm_bt<EPI_BF16, 128, 64><<<32 * 16, 256, 0, stream>>>(hb, wqxb + (size_t)l * 1048576,
        bq + (l * 2 + 1) * 1024, 1024, 1024, 16, qb, nullptr, nullptr);
    vt_kernel<<<gVt, 256, 0, stream>>>(kvb + l * 2048 + 1024, 6144, vtb);
    attn_kernel<false><<<gAttn, 64, 0, stream>>>(qb, 1024, kvb + l * 2048, 6144, vtb, hb);
    gemm_bt<EPI_RES2, 128, 64><<<32 * 16, 256, 0, stream>>>(hb, Wob + (size_t)(l * 2 + 1) * 1048576,
        bo + (l * 2 + 1) * 1024, 1024, 1024, 16, c, x, x);

    // ---- FFN sublayer (residual is c, per reference quirk) ----
    ln_kernel<<<4096, 64, 0, stream>>>(x, g2, e2, hb);
    gemm256<1><<<32 * 16, 512, 0, stream>>>(hb, W1b + (size_t)l * 4194304,
        b1 + l * 4096, 4096, mid);
    float* xout = (l == 2) ? (float*)d_out : x;
    gemm_bt<EPI_RES, 128, 64><<<32 * 16, 256, 0, stream>>>(mid, W2b + (size_t)l * 4194304,
        b2 + l * 1024, 1024, 4096, 16, xout, c, nullptr);
  }
}

// Round 11
// 1140.194 us; speedup vs baseline: 1.1799x; 1.0372x over previous
//
#include <hip/hip_runtime.h>
#include <hip/hip_bf16.h>

using bf16x8 = __attribute__((ext_vector_type(8))) short;
using f32x4  = __attribute__((ext_vector_type(4))) float;
using u16x4  = __attribute__((ext_vector_type(4))) unsigned short;

#define DEVI static __device__ __forceinline__

DEVI unsigned short f2b(float f) {           // f32 -> bf16 RNE
  unsigned int u = __float_as_uint(f);
  u += 0x7FFFu + ((u >> 16) & 1u);
  return (unsigned short)(u >> 16);
}

DEVI void gload16(const unsigned short* g, unsigned short* l) {
  __builtin_amdgcn_global_load_lds(
      (const __attribute__((address_space(1))) unsigned int*)g,
      (__attribute__((address_space(3))) unsigned int*)l, 16, 0, 0);
}

DEVI float wred_max16(float v) {
#pragma unroll
  for (int m = 1; m < 16; m <<= 1) v = fmaxf(v, __shfl_xor(v, m, 64));
  return v;
}
DEVI float wred_sum16(float v) {
#pragma unroll
  for (int m = 1; m < 16; m <<= 1) v += __shfl_xor(v, m, 64);
  return v;
}

// ---------------- elementwise / pack kernels ----------------

__global__ void cvt_kernel(const float* __restrict__ in,
                           unsigned short* __restrict__ out, int n4) {
  int i = blockIdx.x * blockDim.x + threadIdx.x;
  const int stride = gridDim.x * blockDim.x;
  for (; i < n4; i += stride) {
    const float4 v = ((const float4*)in)[i];
    u16x4 o;
    o[0] = f2b(v.x); o[1] = f2b(v.y); o[2] = f2b(v.z); o[3] = f2b(v.w);
    ((u16x4*)out)[i] = o;
  }
}

// Pack rows of up to 3 source weight tensors ([L][2][1024][1024] f32, sub-slot
// `sub`) into a fused bf16 buffer dst[l][nm*1024][1024].
__global__ void pack_w(const float* __restrict__ s0,
                       const float* __restrict__ s1,
                       const float* __restrict__ s2,
                       int sub, unsigned short* __restrict__ dst, int nm) {
  const int r = blockIdx.x;      // row 0..1023
  const int m = blockIdx.y;      // matrix slot
  const int l = blockIdx.z;      // layer
  const float* src = (m == 0 ? s0 : m == 1 ? s1 : s2)
                   + (size_t)(l * 2 + sub) * 1048576 + (size_t)r * 1024;
  unsigned short* d = dst + ((size_t)(l * nm + m) * 1024 + r) * 1024;
  const int col = threadIdx.x * 4;
  const float4 v = *(const float4*)(src + col);
  u16x4 o;
  o[0] = f2b(v.x); o[1] = f2b(v.y); o[2] = f2b(v.z); o[3] = f2b(v.w);
  *(u16x4*)(d + col) = o;
}

__global__ void pack_bias(const float* __restrict__ s0,
                          const float* __restrict__ s1,
                          const float* __restrict__ s2,
                          int sub, float* __restrict__ dst, int nm) {
  const int m = blockIdx.x, l = blockIdx.y;
  const float* src = (m == 0 ? s0 : m == 1 ? s1 : s2) + (size_t)(l * 2 + sub) * 1024;
  float* d = dst + ((size_t)l * nm + m) * 1024;
  const int i = threadIdx.x * 4;
  *(float4*)(d + i) = *(const float4*)(src + i);
}

__global__ void embed_kernel(const int* __restrict__ ids,
                             const float* __restrict__ emb,
                             const float* __restrict__ pe,
                             float* __restrict__ x) {
  const int row = blockIdx.x;           // b*512 + t
  const int t = row & 511;
  const int col = threadIdx.x * 4;      // 256 threads
  const int id = ids[row];
  const float4 e = *(const float4*)(emb + (size_t)id * 1024 + col);
  const float4 p = *(const float4*)(pe + (size_t)t * 1024 + col);
  float4 o;
  o.x = e.x * 32.f + p.x; o.y = e.y * 32.f + p.y;
  o.z = e.z * 32.f + p.z; o.w = e.w * 32.f + p.w;
  *(float4*)(x + (size_t)row * 1024 + col) = o;
}

__global__ void ln_kernel(const float* __restrict__ x,
                          const float* __restrict__ g,
                          const float* __restrict__ b,
                          unsigned short* __restrict__ out) {
  const int row = blockIdx.x;
  const int l = threadIdx.x;            // 64 lanes, 16 elems each
  const float4* xr = (const float4*)(x + (size_t)row * 1024);
  float4 v[4];
  float s = 0.f;
#pragma unroll
  for (int i = 0; i < 4; ++i) {
    v[i] = xr[l * 4 + i];
    s += v[i].x + v[i].y + v[i].z + v[i].w;
  }
#pragma unroll
  for (int m = 1; m < 64; m <<= 1) s += __shfl_xor(s, m, 64);
  const float mean = s * (1.f / 1024.f);
  float vs = 0.f;
#pragma unroll
  for (int i = 0; i < 4; ++i) {
    float dx = v[i].x - mean, dy = v[i].y - mean, dz = v[i].z - mean, dw = v[i].w - mean;
    vs += dx * dx + dy * dy + dz * dz + dw * dw;
  }
#pragma unroll
  for (int m = 1; m < 64; m <<= 1) vs += __shfl_xor(vs, m, 64);
  const float inv = rsqrtf(vs * (1.f / 1024.f) + 1e-5f);
#pragma unroll
  for (int i = 0; i < 4; ++i) {
    const int col = l * 16 + i * 4;
    const float4 gg = *(const float4*)(g + col);
    const float4 bb = *(const float4*)(b + col);
    u16x4 o;
    o[0] = f2b((v[i].x - mean) * inv * gg.x + bb.x);
    o[1] = f2b((v[i].y - mean) * inv * gg.y + bb.y);
    o[2] = f2b((v[i].z - mean) * inv * gg.z + bb.z);
    o[3] = f2b((v[i].w - mean) * inv * gg.w + bb.w);
    *(u16x4*)(out + (size_t)row * 1024 + col) = o;
  }
}

// Transpose per-head V into Vt[b][h][d=64][t=512] for vectorized PV loads.
__global__ void vt_kernel(const unsigned short* __restrict__ Vsrc, int vsd,
                          unsigned short* __restrict__ Vt) {
  __shared__ alignas(16) unsigned short t[64][72];
  const int tt = blockIdx.x;     // token tile 0..7
  const int h  = blockIdx.y;
  const int b  = blockIdx.z;
  const int tid = threadIdx.x;
  const int r  = tid >> 2;       // token in tile (0..63)
  const int ch = tid & 3;        // 16-elem d chunk (0..3)
  const unsigned short* src =
      Vsrc + (size_t)(b * 512 + tt * 64 + r) * vsd + (size_t)h * 64 + ch * 16;
  const bf16x8 v0 = *(const bf16x8*)src;
  const bf16x8 v1 = *(const bf16x8*)(src + 8);
#pragma unroll
  for (int j = 0; j < 8; ++j) {
    t[ch * 16 + j][r]     = (unsigned short)v0[j];
    t[ch * 16 + 8 + j][r] = (unsigned short)v1[j];
  }
  __syncthreads();
  const int d  = tid >> 2;       // d (0..63)
  const int tp = tid & 3;        // token sub-chunk (16 tokens)
  unsigned short* dst = Vt + (((size_t)(b * 16 + h) * 64 + d) * 512) + tt * 64 + tp * 16;
  *(bf16x8*)dst       = *(const bf16x8*)&t[d][tp * 16];
  *(bf16x8*)(dst + 8) = *(const bf16x8*)&t[d][tp * 16 + 8];
}

// ------------- fat GEMM: 256x128 tile, 8 waves, 3-slot LDS ring -------------

template<int EPI>  // 0 = bf16, 1 = relu+bf16
__global__ __launch_bounds__(512, 2) void gemm256(
    const unsigned short* __restrict__ A,
    const unsigned short* __restrict__ Bw,
    const float* __restrict__ bias,
    int N, unsigned short* __restrict__ out0) {
  constexpr int K = 1024, NK = 16;
  __shared__ alignas(16) unsigned short As0[256 * 64];
  __shared__ alignas(16) unsigned short As1[256 * 64];
  __shared__ alignas(16) unsigned short As2[256 * 64];
  __shared__ alignas(16) unsigned short Bs0[128 * 64];
  __shared__ alignas(16) unsigned short Bs1[128 * 64];
  __shared__ alignas(16) unsigned short Bs2[128 * 64];
  const int tid = threadIdx.x;
  const int lane = tid & 63;
  const int wave = tid >> 6;
  const int wr = wave >> 2;
  const int wc = wave & 3;
  int id = blockIdx.x;
  const int nwg = gridDim.x;
  id = (id & 7) * (nwg >> 3) + (id >> 3);
  const int nn = N >> 7;
  const int bx = id % nn;
  const int by = id / nn;
  const int m0 = by * 256;
  const int n0 = bx * 128;
  const int ro = lane & 15;
  const int hi = lane >> 4;

  auto stageA = [&](unsigned short* dst, int kt) {
    const size_t k0 = (size_t)kt * 64;
#pragma unroll
    for (int i = 0; i < 4; ++i) {
      const int c = tid + 512 * i;
      const int row = c >> 3;
      const int lc = (c & 7) ^ (row & 7);
      gload16(A + (size_t)(m0 + row) * K + k0 + lc * 8, dst + c * 8);
    }
  };
  auto stageB = [&](unsigned short* dst, int kt) {
    const size_t k0 = (size_t)kt * 64;
#pragma unroll
    for (int i = 0; i < 2; ++i) {
      const int c = tid + 512 * i;
      const int row = c >> 3;
      const int lc = (c & 7) ^ (row & 7);
      gload16(Bw + (size_t)(n0 + row) * K + k0 + lc * 8, dst + c * 8);
    }
  };

  f32x4 acc[8][2];
#pragma unroll
  for (int i = 0; i < 8; ++i)
#pragma unroll
    for (int j = 0; j < 2; ++j) acc[i][j] = f32x4{0.f, 0.f, 0.f, 0.f};

  stageA(As0, 0); stageB(Bs0, 0);
  stageA(As1, 1); stageB(Bs1, 1);

  auto body = [&](int kt, const unsigned short* Ac, const unsigned short* Bc,
                  unsigned short* An, unsigned short* Bn, bool last) {
    if (last) asm volatile("s_waitcnt vmcnt(0)" ::: "memory");
    else      asm volatile("s_waitcnt vmcnt(6)" ::: "memory");
    __builtin_amdgcn_s_barrier();
    if (kt + 2 < NK) { stageA(An, kt + 2); stageB(Bn, kt + 2); }
    bf16x8 af[8][2], bf[2][2];
#pragma unroll
    for (int mi = 0; mi < 8; ++mi) {
      const int r = wr * 128 + mi * 16 + ro;
#pragma unroll
      for (int ks = 0; ks < 2; ++ks)
        af[mi][ks] = *(const bf16x8*)&Ac[r * 64 + (((ks << 2) + hi) ^ (r & 7)) * 8];
    }
#pragma unroll
    for (int nj = 0; nj < 2; ++nj) {
      const int r = wc * 32 + nj * 16 + ro;
#pragma unroll
      for (int ks = 0; ks < 2; ++ks)
        bf[nj][ks] = *(const bf16x8*)&Bc[r * 64 + (((ks << 2) + hi) ^ (r & 7)) * 8];
    }
    __builtin_amdgcn_s_setprio(1);
#pragma unroll
    for (int ks = 0; ks < 2; ++ks)
#pragma unroll
      for (int mi = 0; mi < 8; ++mi)
#pragma unroll
        for (int nj = 0; nj < 2; ++nj)
          acc[mi][nj] = __builtin_amdgcn_mfma_f32_16x16x32_bf16(af[mi][ks], bf[nj][ks], acc[mi][nj], 0, 0, 0);
    __builtin_amdgcn_s_setprio(0);
  };

  for (int base = 0; base < 15; base += 3) {
    body(base,     As0, Bs0, As2, Bs2, false);
    body(base + 1, As1, Bs1, As0, Bs0, false);
    body(base + 2, As2, Bs2, As1, Bs1, false);
  }
  body(15, As0, Bs0, As1, Bs1, true);

  const int r4 = hi * 4;
#pragma unroll
  for (int mi = 0; mi < 8; ++mi) {
#pragma unroll
    for (int nj = 0; nj < 2; ++nj) {
      const int cg = n0 + wc * 32 + nj * 16 + ro;
      const float bv = bias[cg];
#pragma unroll
      for (int q = 0; q < 4; ++q) {
        const int rg = m0 + wr * 128 + mi * 16 + r4 + q;
        const float v = acc[mi][nj][q] + bv;
        out0[(size_t)rg * N + cg] = f2b(EPI == 1 ? fmaxf(v, 0.f) : v);
      }
    }
  }
}

// ---------------- skinny GEMM (R7 structure, BM=128, BN=64) ----------------

enum { EPI_BF16 = 0, EPI_RELU_BF16 = 1, EPI_RES = 2, EPI_RES2 = 3 };

template<int EPI, int BM, int BN>
__global__ void gemm_bt(const unsigned short* __restrict__ A,
                        const unsigned short* __restrict__ Bw,
                        const float* __restrict__ bias,
                        int N, int K, int nn,
                        void* out0, const float* res, float* out1) {
  constexpr int MI = BM / 32;
  constexpr int NJ = BN / 32;
  __shared__ alignas(16) unsigned short As[2][BM * 64];
  __shared__ alignas(16) unsigned short Bs[2][BN * 64];
  const int tid = threadIdx.x;
  const int lane = tid & 63;
  const int wave = tid >> 6;
  int id = blockIdx.x;
  const int nwg = gridDim.x;
  id = (id & 7) * (nwg >> 3) + (id >> 3);
  const int bx = id % nn;
  const int by = id / nn;
  const int m0 = by * BM;
  const int n0 = bx * BN;
  const int wm = (wave >> 1) * (BM / 2);
  const int wn = (wave & 1) * (BN / 2);

  auto stage = [&](int buf, int kt) {
    const size_t k0 = (size_t)kt * 64;
#pragma unroll
    for (int i = 0; i < MI; ++i) {
      const int c = tid + 256 * i;
      const int row = c >> 3;
      const int lc = (c & 7) ^ (row & 7);
      gload16(A + (size_t)(m0 + row) * K + k0 + lc * 8, &As[buf][c * 8]);
    }
#pragma unroll
    for (int i = 0; i < NJ; ++i) {
      const int c = tid + 256 * i;
      const int row = c >> 3;
      const int lc = (c & 7) ^ (row & 7);
      gload16(Bw + (size_t)(n0 + row) * K + k0 + lc * 8, &Bs[buf][c * 8]);
    }
  };

  f32x4 acc[MI][NJ];
#pragma unroll
  for (int i = 0; i < MI; ++i)
#pragma unroll
    for (int j = 0; j < NJ; ++j) acc[i][j] = f32x4{0.f, 0.f, 0.f, 0.f};

  const int nk = K >> 6;
  stage(0, 0);
  int cur = 0;
  const int ro = lane & 15;
  const int hi = lane >> 4;
  for (int kt = 0; kt < nk; ++kt) {
    __syncthreads();
    if (kt + 1 < nk) stage(cur ^ 1, kt + 1);
    bf16x8 af[MI][2], bf[NJ][2];
#pragma unroll
    for (int i = 0; i < MI; ++i) {
      const int r = wm + i * 16 + ro;
#pragma unroll
      for (int ks = 0; ks < 2; ++ks)
        af[i][ks] = *(const bf16x8*)&As[cur][r * 64 + (((ks << 2) + hi) ^ (r & 7)) * 8];
    }
#pragma unroll
    for (int j = 0; j < NJ; ++j) {
      const int r = wn + j * 16 + ro;
#pragma unroll
      for (int ks = 0; ks < 2; ++ks)
        bf[j][ks] = *(const bf16x8*)&Bs[cur][r * 64 + (((ks << 2) + hi) ^ (r & 7)) * 8];
    }
#pragma unroll
    for (int ks = 0; ks < 2; ++ks)
#pragma unroll
      for (int i = 0; i < MI; ++i)
#pragma unroll
        for (int j = 0; j < NJ; ++j)
          acc[i][j] = __builtin_amdgcn_mfma_f32_16x16x32_bf16(af[i][ks], bf[j][ks], acc[i][j], 0, 0, 0);
    cur ^= 1;
  }

  const int r4 = hi * 4;
#pragma unroll
  for (int i = 0; i < MI; ++i) {
#pragma unroll
    for (int j = 0; j < NJ; ++j) {
      const int cg = n0 + wn + j * 16 + ro;
      const float bv = bias[cg];
#pragma unroll
      for (int q = 0; q < 4; ++q) {
        const int rg = m0 + wm + i * 16 + r4 + q;
        const size_t idx = (size_t)rg * N + cg;
        const float v = acc[i][j][q] + bv;
        if (EPI == EPI_BF16) {
          ((unsigned short*)out0)[idx] = f2b(v);
        } else if (EPI == EPI_RELU_BF16) {
          ((unsigned short*)out0)[idx] = f2b(fmaxf(v, 0.f));
        } else if (EPI == EPI_RES) {
          ((float*)out0)[idx] = res[idx] + v;
        } else {
          const float r = res[idx];
          ((float*)out0)[idx] = v;
          out1[idx] = r + v;
        }
      }
    }
  }
}

// ---------------- fused flash attention (4-wave, LDS-staged K/V) ----------------
// Block = 256 threads (4 waves); block covers 128 q-rows of one (b,h); each
// wave owns a 32-row q-tile. K (64x64) and Vt (64d x 64t) tiles are staged
// cooperatively into double-buffered LDS (XOR-swizzled, conflict-free
// ds_read_b128), one __syncthreads per tile. Fully-masked diagonal tiles are
// skipped per-wave (no barrier inside the skip).

template<bool CAUSAL>
__global__ __launch_bounds__(256) void attn_kernel(
    const unsigned short* __restrict__ Qg, int qs,
    const unsigned short* __restrict__ Kg, int ksd,
    const unsigned short* __restrict__ Vt,
    unsigned short* __restrict__ Og) {
  __shared__ alignas(16) unsigned short Ks[2][64 * 64];
  __shared__ alignas(16) unsigned short Vs[2][64 * 64];
  __shared__ alignas(16) unsigned short Pl[4][32 * 64];
  const int qt0 = blockIdx.x;      // 0..3 (128-row q block)
  const int h  = blockIdx.y;
  const int b  = blockIdx.z;
  const int tid = threadIdx.x;
  const int lane = tid & 63;
  const int w = tid >> 6;
  const int ro = lane & 15;
  const int hi = lane >> 4;
  const int qrow0 = qt0 * 128 + w * 32;
  const size_t qbase = (size_t)b * 512 * qs  + (size_t)h * 64;
  const size_t kbase = (size_t)b * 512 * ksd + (size_t)h * 64;
  const size_t vbase = ((size_t)(b * 16 + h)) * 64 * 512;
  const size_t obase = (size_t)b * 512 * 1024 + (size_t)h * 64;

  bf16x8 qf[2][2];
#pragma unroll
  for (int mi = 0; mi < 2; ++mi)
#pragma unroll
    for (int ks = 0; ks < 2; ++ks)
      qf[mi][ks] = *(const bf16x8*)&Qg[qbase + (size_t)(qrow0 + mi * 16 + ro) * qs + ks * 32 + hi * 8];

  f32x4 o[2][4];
  float mrun[2][4], lrun[2][4];
#pragma unroll
  for (int mi = 0; mi < 2; ++mi) {
#pragma unroll
    for (int di = 0; di < 4; ++di) o[mi][di] = f32x4{0.f, 0.f, 0.f, 0.f};
#pragma unroll
    for (int q = 0; q < 4; ++q) { mrun[mi][q] = -1e30f; lrun[mi][q] = 0.f; }
  }

  auto stage = [&](int buf, int kt) {
#pragma unroll
    for (int i = 0; i < 2; ++i) {             // K: 64 rows x 8 chunks
      const int c = tid + 256 * i;
      const int row = c >> 3;
      const int lc = (c & 7) ^ (row & 7);
      gload16(Kg + kbase + (size_t)(kt * 64 + row) * ksd + lc * 8, &Ks[buf][c * 8]);
    }
#pragma unroll
    for (int i = 0; i < 2; ++i) {             // V: 64 d-rows x 8 chunks
      const int c = tid + 256 * i;
      const int row = c >> 3;
      const int lc = (c & 7) ^ (row & 7);
      gload16(Vt + vbase + (size_t)row * 512 + (size_t)kt * 64 + lc * 8, &Vs[buf][c * 8]);
    }
  };

  const int ktmax = CAUSAL ? (qt0 * 2 + 1) : 7;
  stage(0, 0);
  int cur = 0;
  for (int kt = 0; kt <= ktmax; ++kt) {
    __syncthreads();                  // stage(cur) landed; prior reads drained
    if (kt < ktmax) stage(cur ^ 1, kt + 1);
    const bool skip = CAUSAL && (kt * 64 > qrow0 + 31);  // tile fully masked for this wave
    if (!skip) {
      bf16x8 kf[4][2];
#pragma unroll
      for (int ni = 0; ni < 4; ++ni) {
        const int r = ni * 16 + ro;
#pragma unroll
        for (int ks = 0; ks < 2; ++ks)
          kf[ni][ks] = *(const bf16x8*)&Ks[cur][r * 64 + (((ks << 2) + hi) ^ (r & 7)) * 8];
      }

      f32x4 s[2][4];
#pragma unroll
      for (int mi = 0; mi < 2; ++mi)
#pragma unroll
        for (int ni = 0; ni < 4; ++ni) s[mi][ni] = f32x4{0.f, 0.f, 0.f, 0.f};
#pragma unroll
      for (int ks = 0; ks < 2; ++ks)
#pragma unroll
        for (int mi = 0; mi < 2; ++mi)
#pragma unroll
          for (int ni = 0; ni < 4; ++ni)
            s[mi][ni] = __builtin_amdgcn_mfma_f32_16x16x32_bf16(qf[mi][ks], kf[ni][ks], s[mi][ni], 0, 0, 0);

      const bool dm = CAUSAL && (kt * 64 + 63 > qrow0);
#pragma unroll
      for (int mi = 0; mi < 2; ++mi)
#pragma unroll
        for (int ni = 0; ni < 4; ++ni)
#pragma unroll
          for (int q = 0; q < 4; ++q) {
            float e = s[mi][ni][q] * 0.125f;
            if (dm && (kt * 64 + ni * 16 + ro) > (qrow0 + mi * 16 + hi * 4 + q)) e = -1e9f;
            s[mi][ni][q] = e;
          }

      float fac[2][4];
#pragma unroll
      for (int mi = 0; mi < 2; ++mi)
#pragma unroll
        for (int q = 0; q < 4; ++q) {
          float rm = s[mi][0][q];
#pragma unroll
          for (int ni = 1; ni < 4; ++ni) rm = fmaxf(rm, s[mi][ni][q]);
          rm = wred_max16(rm);
          const float mn = fmaxf(mrun[mi][q], rm);
          fac[mi][q] = __expf(mrun[mi][q] - mn);
          mrun[mi][q] = mn;
        }
#pragma unroll
      for (int mi = 0; mi < 2; ++mi)
#pragma unroll
        for (int q = 0; q < 4; ++q) {
          float rs = 0.f;
#pragma unroll
          for (int ni = 0; ni < 4; ++ni) {
            const float pv = __expf(s[mi][ni][q] - mrun[mi][q]);
            s[mi][ni][q] = pv;
            rs += pv;
          }
          rs = wred_sum16(rs);
          lrun[mi][q] = lrun[mi][q] * fac[mi][q] + rs;
        }
#pragma unroll
      for (int mi = 0; mi < 2; ++mi)
#pragma unroll
        for (int di = 0; di < 4; ++di)
#pragma unroll
          for (int q = 0; q < 4; ++q) o[mi][di][q] *= fac[mi][q];

      // P -> per-wave LDS (XOR-swizzled), read back as A-fragments
#pragma unroll
      for (int mi = 0; mi < 2; ++mi)
#pragma unroll
        for (int ni = 0; ni < 4; ++ni)
#pragma unroll
          for (int q = 0; q < 4; ++q) {
            const int row = mi * 16 + hi * 4 + q;
            const int col = ni * 16 + ro;
            const int sc  = ((col >> 3) ^ (row & 7)) * 8 + (col & 7);
            Pl[w][row * 64 + sc] = f2b(s[mi][ni][q]);
          }

      bf16x8 pa[2][2];
#pragma unroll
      for (int mi = 0; mi < 2; ++mi)
#pragma unroll
        for (int ks = 0; ks < 2; ++ks) {
          const int row = mi * 16 + ro;
          pa[mi][ks] = *(const bf16x8*)&Pl[w][row * 64 + (((ks << 2) + hi) ^ (row & 7)) * 8];
        }

#pragma unroll
      for (int di = 0; di < 4; ++di)
#pragma unroll
        for (int ks = 0; ks < 2; ++ks) {
          const int r = di * 16 + ro;
          const bf16x8 vf = *(const bf16x8*)&Vs[cur][r * 64 + (((ks << 2) + hi) ^ (r & 7)) * 8];
#pragma unroll
          for (int mi = 0; mi < 2; ++mi)
            o[mi][di] = __builtin_amdgcn_mfma_f32_16x16x32_bf16(pa[mi][ks], vf, o[mi][di], 0, 0, 0);
        }
    }
    cur ^= 1;
  }

#pragma unroll
  for (int mi = 0; mi < 2; ++mi)
#pragma unroll
    for (int di = 0; di < 4; ++di)
#pragma unroll
      for (int q = 0; q < 4; ++q) {
        const float val = o[mi][di][q] / lrun[mi][q];
        Og[obase + (size_t)(qrow0 + mi * 16 + hi * 4 + q) * 1024 + di * 16 + ro] = f2b(val);
      }
}

// ---------------- host orchestration ----------------

extern "C" void kernel_launch(void* const* d_in, const int* in_sizes, int n_in,
                              void* d_out, int out_size, void* d_ws, size_t ws_size,
                              hipStream_t stream) {
  (void)in_sizes; (void)n_in; (void)out_size; (void)ws_size;
  const int*   dec = (const int*)d_in[0];
  const float* enc = (const float*)d_in[2];
  const float* emb = (const float*)d_in[4];
  const float* pe  = (const float*)d_in[5];
  const float* wq  = (const float*)d_in[6];
  const float* bq  = (const float*)d_in[7];
  const float* wk  = (const float*)d_in[8];
  const float* bk  = (const float*)d_in[9];
  const float* wv  = (const float*)d_in[10];
  const float* bv  = (const float*)d_in[11];
  const float* wo  = (const float*)d_in[12];
  const float* bo  = (const float*)d_in[13];
  const float* w1  = (const float*)d_in[14];
  const float* b1  = (const float*)d_in[15];
  const float* w2  = (const float*)d_in[16];
  const float* b2  = (const float*)d_in[17];
  const float* lng = (const float*)d_in[18];
  const float* lnb = (const float*)d_in[19];

  const size_t SZ_ACT = 4194304ull;     // 4096*1024

  char* p = (char*)d_ws;
  auto alloc = [&](size_t bytes) { char* r = p; p += (bytes + 255) & ~(size_t)255; return r; };
  unsigned short* qkvw  = (unsigned short*)alloc(3ull * 3 * 1048576 * 2);  // [L][3072][1024]
  unsigned short* kvw   = (unsigned short*)alloc(3ull * 2 * 1048576 * 2);  // [6144][1024]
  unsigned short* wqxb  = (unsigned short*)alloc(3ull * 1048576 * 2);      // [L][1024][1024]
  unsigned short* Wob   = (unsigned short*)alloc(6291456ull * 2);          // [L][2][1024][1024]
  unsigned short* W1b   = (unsigned short*)alloc(12582912ull * 2);
  unsigned short* W2b   = (unsigned short*)alloc(12582912ull * 2);
  unsigned short* encb  = (unsigned short*)alloc(SZ_ACT * 2);
  float*          x     = (float*)alloc(SZ_ACT * 4);
  float*          c     = (float*)alloc(SZ_ACT * 4);
  unsigned short* hb    = (unsigned short*)alloc(SZ_ACT * 2);
  unsigned short* qkvb  = (unsigned short*)alloc(4096ull * 3072 * 2);
  unsigned short* kvb   = (unsigned short*)alloc(4096ull * 6144 * 2);      // merged 3-layer K/V
  unsigned short* qb    = (unsigned short*)alloc(SZ_ACT * 2);
  unsigned short* vtb   = (unsigned short*)alloc(SZ_ACT * 2);              // [B][H][64][512]
  unsigned short* mid   = (unsigned short*)alloc(4096ull * 4096 * 2);
  float*          qkvbias = (float*)alloc(3ull * 3072 * 4);
  float*          kvbias  = (float*)alloc(3ull * 2048 * 4);

  cvt_kernel<<<2048, 256, 0, stream>>>(wo, Wob, 1572864);
  cvt_kernel<<<2048, 256, 0, stream>>>(w1, W1b, 3145728);
  cvt_kernel<<<2048, 256, 0, stream>>>(w2, W2b, 3145728);
  cvt_kernel<<<2048, 256, 0, stream>>>(enc, encb, 1048576);
  pack_w<<<dim3(1024, 3, 3), 256, 0, stream>>>(wq, wk, wv, 0, qkvw, 3);
  pack_w<<<dim3(1024, 2, 3), 256, 0, stream>>>(wk, wv, wv, 1, kvw, 2);
  pack_w<<<dim3(1024, 1, 3), 256, 0, stream>>>(wq, wq, wq, 1, wqxb, 1);
  pack_bias<<<dim3(3, 3), 256, 0, stream>>>(bq, bk, bv, 0, qkvbias, 3);
  pack_bias<<<dim3(2, 3), 256, 0, stream>>>(bk, bv, bv, 1, kvbias, 2);
  embed_kernel<<<4096, 256, 0, stream>>>(dec, emb, pe, x);

  // merged cross-attn K/V for all 3 layers: [4096][6144]
  gemm256<0><<<48 * 16, 512, 0, stream>>>(encb, kvw, kvbias, 6144, kvb);

  const dim3 gAttn(4, 16, 8);
  const dim3 gVt(8, 16, 8);

  for (int l = 0; l < 3; ++l) {
    const float* g0 = lng + (l * 3 + 0) * 1024; const float* e0 = lnb + (l * 3 + 0) * 1024;
    const float* g1 = lng + (l * 3 + 1) * 1024; const float* e1 = lnb + (l * 3 + 1) * 1024;
    const float* g2 = lng + (l * 3 + 2) * 1024; const float* e2 = lnb + (l * 3 + 2) * 1024;

    // ---- self-attention sublayer ----
    ln_kernel<<<4096, 64, 0, stream>>>(x, g0, e0, hb);
    gemm256<0><<<24 * 16, 512, 0, stream>>>(hb, qkvw + (size_t)l * 3 * 1048576,
        qkvbias + l * 3072, 3072, qkvb);
    vt_kernel<<<gVt, 256, 0, stream>>>(qkvb + 2048, 3072, vtb);
    attn_kernel<true><<<gAttn, 256, 0, stream>>>(qkvb, 3072, qkvb + 1024, 3072, vtb, hb);
    gemm_bt<EPI_RES, 128, 64><<<32 * 16, 256, 0, stream>>>(hb, Wob + (size_t)(l * 2) * 1048576,
        bo + (l * 2) * 1024, 1024, 1024, 16, x, x, nullptr);

    // ---- cross-attention sublayer ----
    ln_kernel<<<4096, 64, 0, stream>>>(x, g1, e1, hb);
    gemm_bt<EPI_BF16, 128, 64><<<32 * 16, 256, 0, stream>>>(hb, wqxb + (size_t)l * 1048576,
        bq + (l * 2 + 1) * 1024, 1024, 1024, 16, qb, nullptr, nullptr);
    vt_kernel<<<gVt, 256, 0, stream>>>(kvb + l * 2048 + 1024, 6144, vtb);
    attn_kernel<false><<<gAttn, 256, 0, stream>>>(qb, 1024, kvb + l * 2048, 6144, vtb, hb);
    gemm_bt<EPI_RES2, 128, 64><<<32 * 16, 256, 0, stream>>>(hb, Wob + (size_t)(l * 2 + 1) * 1048576,
        bo + (l * 2 + 1) * 1024, 1024, 1024, 16, c, x, x);

    // ---- FFN sublayer (residual is c, per reference quirk) ----
    ln_kernel<<<4096, 64, 0, stream>>>(x, g2, e2, hb);
    gemm256<1><<<32 * 16, 512, 0, stream>>>(hb, W1b + (size_t)l * 4194304,
        b1 + l * 4096, 4096, mid);
    float* xout = (l == 2) ? (float*)d_out : x;
    gemm_bt<EPI_RES, 128, 64><<<32 * 16, 256, 0, stream>>>(mid, W2b + (size_t)l * 4194304,
        b2 + l * 1024, 1024, 4096, 16, xout, c, nullptr);
  }
}